// Round 4
// baseline (57.152 us; speedup 1.0000x reference)
//
#include <hip/hip_runtime.h>
#include <hip/hip_bf16.h>

#define BS_   256
#define NOPS_ 2000
#define NJ_   50
#define NM_   40
#define E_    128
#define H_    128
#define NCOL_ 2001   // 1 + 50*40

typedef _Float16 f16;
using f16x8 = __attribute__((ext_vector_type(8))) _Float16;
using f32x4 = __attribute__((ext_vector_type(4))) float;

// ws layout (f16 element offsets unless noted):
//   ws1  [0, 32768)            W1T f16 [h=128][e=256]
//   ws2  [32768, 49152)        W2T f16 [n=128][k=128]
//   wsJ  [49152, 1687552)      jp f16 [b=256][50][128]
//   wsM  [1687552, 2998272)    mp f16 [b=256][40][128]  (b1 folded in)
//   wsn  float at byte 5996544 (noop logit)
#define WS1_E   0
#define WS2_E   32768
#define WSJ_E   49152
#define WSM_E   1687552
#define WSN_B   5996544

// ---------------------------------------------------------------------------
// K1: weight transpose+convert to f16, noop logit
// ---------------------------------------------------------------------------
__global__ __launch_bounds__(256) void fjsp_prep(
    const float* __restrict__ dummy,
    const float* __restrict__ W1, const float* __restrict__ b1,
    const float* __restrict__ W2, const float* __restrict__ b2,
    const float* __restrict__ W3, const float* __restrict__ b3,
    f16* __restrict__ ws, float* __restrict__ wsn)
{
  const int blk = blockIdx.x, tid = threadIdx.x;
  if (blk < 8) {
    f16* ws1 = ws + WS1_E;
    const int h = tid & 127, esub = tid >> 7, e0 = blk * 32;
    #pragma unroll
    for (int p = 0; p < 16; ++p) {
      const int e = e0 + 2 * p + esub;
      ws1[h * 256 + e] = (f16)W1[(size_t)e * H_ + h];
    }
  } else if (blk < 12) {
    f16* ws2 = ws + WS2_E;
    const int n = tid & 127, ksub = tid >> 7, k0 = (blk - 8) * 32;
    #pragma unroll
    for (int p = 0; p < 16; ++p) {
      const int k = k0 + 2 * p + ksub;
      ws2[n * 128 + k] = (f16)W2[(size_t)k * H_ + n];
    }
  } else {
    __shared__ float dtmp[128];
    __shared__ float wsum[2];
    if (tid < H_) {
      float s = b1[tid];
      for (int e = 0; e < 2 * E_; ++e) s += dummy[e] * W1[(size_t)e * H_ + tid];
      dtmp[tid] = fmaxf(s, 0.f);
    }
    __syncthreads();
    float nv = 0.f;
    if (tid < H_) {
      float s = b2[tid];
      for (int k = 0; k < H_; ++k) s += dtmp[k] * W2[(size_t)k * H_ + tid];
      nv = fmaxf(s, 0.f) * W3[tid];
    }
    #pragma unroll
    for (int s = 1; s < 64; s <<= 1) nv += __shfl_xor(nv, s);
    if (tid < 128 && (tid & 63) == 0) wsum[tid >> 6] = nv;
    __syncthreads();
    if (tid == 0) wsn[0] = wsum[0] + wsum[1] + b3[0];
  }
}

// ---------------------------------------------------------------------------
// K2: per-batch projections  jp = gather(ops)@W1[:128],  mp = ma@W1[128:]+b1
// one block (256 thr, 4 waves) per batch element; results f16 in ws
// ---------------------------------------------------------------------------
__global__ __launch_bounds__(256) void fjsp_proj(
    const float* __restrict__ ops_emb,
    const float* __restrict__ ma_emb,
    const int*   __restrict__ next_op,
    const float* __restrict__ b1,
    f16* __restrict__ ws)
{
  const int b    = blockIdx.x;
  const int tid  = threadIdx.x;
  const int lane = tid & 63;
  const int wave = tid >> 6;
  const int g    = lane >> 4;
  const int lr   = lane & 15;
  const f16* ws1 = ws + WS1_E;

  // ---- phase J: rows wave*16 + {0..15} (guard < 50) ----
  {
    int jr = wave * 16 + lr; if (jr > NJ_ - 1) jr = NJ_ - 1;
    const int idx = next_op[b * NJ_ + jr];
    const float4* ep = reinterpret_cast<const float4*>(
        ops_emb + ((size_t)b * NOPS_ + idx) * E_);
    f16x8 af[4];
    #pragma unroll
    for (int f = 0; f < 4; ++f) {
      const float4 v0 = ep[8 * f + 2 * g];
      const float4 v1 = ep[8 * f + 2 * g + 1];
      f16x8 a;
      a[0] = (f16)v0.x; a[1] = (f16)v0.y; a[2] = (f16)v0.z; a[3] = (f16)v0.w;
      a[4] = (f16)v1.x; a[5] = (f16)v1.y; a[6] = (f16)v1.z; a[7] = (f16)v1.w;
      af[f] = a;
    }
    f32x4 acc[8];
    #pragma unroll
    for (int c = 0; c < 8; ++c) acc[c] = f32x4{0.f, 0.f, 0.f, 0.f};
    #pragma unroll
    for (int f = 0; f < 4; ++f)
      #pragma unroll
      for (int c = 0; c < 8; ++c) {
        const f16x8 bb = *reinterpret_cast<const f16x8*>(
            ws1 + (size_t)(16 * c + lr) * 256 + 32 * f + 8 * g);
        acc[c] = __builtin_amdgcn_mfma_f32_16x16x32_f16(af[f], bb, acc[c], 0, 0, 0);
      }
    f16* wsJ = ws + WSJ_E + (size_t)b * NJ_ * E_;
    #pragma unroll
    for (int c = 0; c < 8; ++c)
      #pragma unroll
      for (int i = 0; i < 4; ++i) {
        const int row = wave * 16 + 4 * g + i;
        if (row < NJ_) wsJ[row * E_ + 16 * c + lr] = (f16)acc[c][i];
      }
  }

  // ---- phase M: waves 0-2, rows wave*16 + {0..15} (guard < 40), +b1 ----
  if (wave < 3) {
    int mr = wave * 16 + lr; if (mr > NM_ - 1) mr = NM_ - 1;
    const float4* ep = reinterpret_cast<const float4*>(
        ma_emb + ((size_t)b * NM_ + mr) * E_);
    f16x8 af[4];
    #pragma unroll
    for (int f = 0; f < 4; ++f) {
      const float4 v0 = ep[8 * f + 2 * g];
      const float4 v1 = ep[8 * f + 2 * g + 1];
      f16x8 a;
      a[0] = (f16)v0.x; a[1] = (f16)v0.y; a[2] = (f16)v0.z; a[3] = (f16)v0.w;
      a[4] = (f16)v1.x; a[5] = (f16)v1.y; a[6] = (f16)v1.z; a[7] = (f16)v1.w;
      af[f] = a;
    }
    float b1r[8];
    #pragma unroll
    for (int c = 0; c < 8; ++c) b1r[c] = b1[16 * c + lr];
    f32x4 acc[8];
    #pragma unroll
    for (int c = 0; c < 8; ++c)
      acc[c] = f32x4{b1r[c], b1r[c], b1r[c], b1r[c]};
    #pragma unroll
    for (int f = 0; f < 4; ++f)
      #pragma unroll
      for (int c = 0; c < 8; ++c) {
        const f16x8 bb = *reinterpret_cast<const f16x8*>(
            ws1 + (size_t)(16 * c + lr) * 256 + E_ + 32 * f + 8 * g);
        acc[c] = __builtin_amdgcn_mfma_f32_16x16x32_f16(af[f], bb, acc[c], 0, 0, 0);
      }
    f16* wsM = ws + WSM_E + (size_t)b * NM_ * E_;
    #pragma unroll
    for (int c = 0; c < 8; ++c)
      #pragma unroll
      for (int i = 0; i < 4; ++i) {
        const int row = wave * 16 + 4 * g + i;
        if (row < NM_) wsM[row * E_ + 16 * c + lr] = (f16)acc[c][i];
      }
  }
}

// ---------------------------------------------------------------------------
// K3: main pair-logit kernel — 2 blocks (256 thr) per batch element
// ---------------------------------------------------------------------------
__global__ __launch_bounds__(256, 2) void fjsp_main(
    const int*   __restrict__ amask,
    const float* __restrict__ b2,
    const float* __restrict__ W3,
    const float* __restrict__ b3,
    const f16*   __restrict__ ws,
    const float* __restrict__ wsn,
    float* __restrict__ out)
{
  const int bid  = blockIdx.x;
  const int b    = bid >> 1;
  const int sub  = bid & 1;
  const int tid  = threadIdx.x;
  const int lane = tid & 63;
  const int wave = tid >> 6;
  const int g    = lane >> 4;
  const int lr   = lane & 15;

  __shared__ __align__(16) f16 jpL[NJ_][136];
  __shared__ __align__(16) f16 mpL[NM_][136];

  // ---- fill LDS from ws (b128 loads/stores) ----
  {
    const f16x8* srcJ = reinterpret_cast<const f16x8*>(ws + WSJ_E + (size_t)b * NJ_ * E_);
    for (int idx = tid; idx < NJ_ * 16; idx += 256) {
      const int row = idx >> 4, c8 = idx & 15;
      *reinterpret_cast<f16x8*>(&jpL[row][c8 * 8]) = srcJ[idx];
    }
    const f16x8* srcM = reinterpret_cast<const f16x8*>(ws + WSM_E + (size_t)b * NM_ * E_);
    for (int idx = tid; idx < NM_ * 16; idx += 256) {
      const int row = idx >> 4, c8 = idx & 15;
      *reinterpret_cast<f16x8*>(&mpL[row][c8 * 8]) = srcM[idx];
    }
  }

  // ---- W2 fragments (B-operand) + b2/W3 per-column scalars ----
  f16x8 w2f[4][8];
  const f16* ws2 = ws + WS2_E;
  #pragma unroll
  for (int f = 0; f < 4; ++f)
    #pragma unroll
    for (int c = 0; c < 8; ++c)
      w2f[f][c] = *reinterpret_cast<const f16x8*>(
          ws2 + (size_t)(16 * c + lr) * 128 + 32 * f + 8 * g);
  float b2r[8], w3r[8];
  #pragma unroll
  for (int c = 0; c < 8; ++c) { b2r[c] = b2[16 * c + lr]; w3r[c] = W3[16 * c + lr]; }
  const float bias3 = b3[0];

  __syncthreads();

  float* __restrict__ outrow = out + (size_t)b * NCOL_ + 1;
  const int tend = sub ? 125 : 63;

  #pragma unroll 1
  for (int t = sub * 63 + wave; t < tend; t += 4) {
    const int tp0  = t * 16;
    const int rowr = tp0 + lr;
    const int j = rowr / 40;
    const int m = rowr - j * 40;
    f16x8 afr[4];
    #pragma unroll
    for (int f = 0; f < 4; ++f) {
      const f16x8 jv = *reinterpret_cast<const f16x8*>(&jpL[j][32 * f + 8 * g]);
      const f16x8 mv = *reinterpret_cast<const f16x8*>(&mpL[m][32 * f + 8 * g]);
      const f16x8 s  = jv + mv;                       // v_pk_add_f16
      afr[f] = __builtin_elementwise_max(s, (f16x8)(f16)0.0f);  // v_pk_max_f16
    }
    f32x4 acc[8];
    #pragma unroll
    for (int c = 0; c < 8; ++c)
      acc[c] = f32x4{b2r[c], b2r[c], b2r[c], b2r[c]};  // b2 folded into C-init
    #pragma unroll
    for (int f = 0; f < 4; ++f)
      #pragma unroll
      for (int c = 0; c < 8; ++c)
        acc[c] = __builtin_amdgcn_mfma_f32_16x16x32_f16(afr[f], w2f[f][c], acc[c], 0, 0, 0);
    float p0v = 0.f, p1v = 0.f, p2v = 0.f, p3v = 0.f;
    #pragma unroll
    for (int c = 0; c < 8; ++c) {
      p0v = fmaf(fmaxf(acc[c][0], 0.f), w3r[c], p0v);
      p1v = fmaf(fmaxf(acc[c][1], 0.f), w3r[c], p1v);
      p2v = fmaf(fmaxf(acc[c][2], 0.f), w3r[c], p2v);
      p3v = fmaf(fmaxf(acc[c][3], 0.f), w3r[c], p3v);
    }
    #pragma unroll
    for (int s = 1; s < 16; s <<= 1) {
      p0v += __shfl_xor(p0v, s);
      p1v += __shfl_xor(p1v, s);
      p2v += __shfl_xor(p2v, s);
      p3v += __shfl_xor(p3v, s);
    }
    if (lr == 0) {
      const int row = tp0 + 4 * g;
      outrow[row + 0] = p0v + bias3;
      outrow[row + 1] = p1v + bias3;
      outrow[row + 2] = p2v + bias3;
      outrow[row + 3] = p3v + bias3;
    }
  }

  // ---- mask passthrough (int32 bool -> f32), split across the 2 blocks ----
  {
    const int* mrow = amask + (size_t)b * NCOL_;
    float* __restrict__ orow = out + (size_t)BS_ * NCOL_ + (size_t)b * NCOL_;
    const int i0 = sub ? 1001 : 0;
    const int i1 = sub ? NCOL_ : 1001;
    for (int i = i0 + tid; i < i1; i += 256) orow[i] = mrow[i] != 0 ? 1.0f : 0.0f;
  }

  // ---- noop logit ----
  if (sub == 0 && tid == 0) out[(size_t)b * NCOL_] = wsn[0];
}

extern "C" void kernel_launch(void* const* d_in, const int* in_sizes, int n_in,
                              void* d_out, int out_size, void* d_ws, size_t ws_size,
                              hipStream_t stream) {
  (void)in_sizes; (void)n_in; (void)ws_size; (void)out_size;
  f16*   ws  = (f16*)d_ws;
  float* wsn = (float*)((char*)d_ws + WSN_B);

  fjsp_prep<<<dim3(13), dim3(256), 0, stream>>>(
      (const float*)d_in[4],   // dummy
      (const float*)d_in[5],   // W1
      (const float*)d_in[6],   // b1
      (const float*)d_in[7],   // W2
      (const float*)d_in[8],   // b2
      (const float*)d_in[9],   // W3
      (const float*)d_in[10],  // b3
      ws, wsn);

  fjsp_proj<<<dim3(BS_), dim3(256), 0, stream>>>(
      (const float*)d_in[0],   // ops_emb
      (const float*)d_in[1],   // ma_emb
      (const int*)d_in[2],     // next_op
      (const float*)d_in[6],   // b1
      ws);

  fjsp_main<<<dim3(BS_ * 2), dim3(256), 0, stream>>>(
      (const int*)d_in[3],     // action_mask (bool -> int32)
      (const float*)d_in[8],   // b2
      (const float*)d_in[9],   // W3
      (const float*)d_in[10],  // b3
      ws, wsn,
      (float*)d_out);
}

// Round 5
// 55.879 us; speedup vs baseline: 1.0228x; 1.0228x over previous
//
#include <hip/hip_runtime.h>
#include <hip/hip_bf16.h>

#define BS_   256
#define NOPS_ 2000
#define NJ_   50
#define NM_   40
#define E_    128
#define H_    128
#define NCOL_ 2001   // 1 + 50*40

typedef _Float16 f16;
using f16x8 = __attribute__((ext_vector_type(8))) _Float16;
using f32x4 = __attribute__((ext_vector_type(4))) float;

// ws layout (f16 element offsets unless noted):
//   ws1  [0, 32768)            W1T f16 [h=128][e=256]
//   ws2  [32768, 49152)        W2T f16 [n=128][k=128]
//   wsJ  [49152, 1687552)      jp f16 [b=256][50][128]
//   wsM  [1687552, 2998272)    mp f16 [b=256][40][128]  (b1 folded in)
//   wsn  float at byte 5996544 (noop logit)
#define WS1_E   0
#define WS2_E   32768
#define WSJ_E   49152
#define WSM_E   1687552
#define WSN_B   5996544

// ---------------------------------------------------------------------------
// K1: weight transpose+convert to f16, noop logit (parallel, load-pipelined)
// ---------------------------------------------------------------------------
__global__ __launch_bounds__(256) void fjsp_prep(
    const float* __restrict__ dummy,
    const float* __restrict__ W1, const float* __restrict__ b1,
    const float* __restrict__ W2, const float* __restrict__ b2,
    const float* __restrict__ W3, const float* __restrict__ b3,
    f16* __restrict__ ws, float* __restrict__ wsn)
{
  const int blk = blockIdx.x, tid = threadIdx.x;
  if (blk < 8) {
    f16* ws1 = ws + WS1_E;
    const int h = tid & 127, esub = tid >> 7, e0 = blk * 32;
    #pragma unroll
    for (int p = 0; p < 16; ++p) {
      const int e = e0 + 2 * p + esub;
      ws1[h * 256 + e] = (f16)W1[(size_t)e * H_ + h];
    }
  } else if (blk < 12) {
    f16* ws2 = ws + WS2_E;
    const int n = tid & 127, ksub = tid >> 7, k0 = (blk - 8) * 32;
    #pragma unroll
    for (int p = 0; p < 16; ++p) {
      const int k = k0 + 2 * p + ksub;
      ws2[n * 128 + k] = (f16)W2[(size_t)k * H_ + n];
    }
  } else {
    // ---- noop logit, parallel: 2 threads per hidden unit, coalesced ----
    __shared__ float d1s[128];
    __shared__ float red[2];
    const int h = tid & 127, half = tid >> 7;   // half in {0,1}
    float s = 0.f;
    {
      const float* wcol = W1 + (size_t)half * 128 * H_ + h;
      const float* dv   = dummy + half * 128;
      #pragma unroll 16
      for (int e = 0; e < 128; ++e) s = fmaf(dv[e], wcol[(size_t)e * H_], s);
    }
    if (half == 0) d1s[h] = s;
    __syncthreads();
    if (half == 1) d1s[h] = fmaxf(d1s[h] + s + b1[h], 0.f);
    __syncthreads();
    float nv = 0.f;
    if (half == 0) {
      float s2 = b2[h];
      const float* w2col = W2 + h;
      #pragma unroll 16
      for (int k = 0; k < 128; ++k) s2 = fmaf(d1s[k], w2col[(size_t)k * H_], s2);
      nv = fmaxf(s2, 0.f) * W3[h];
    }
    #pragma unroll
    for (int sft = 1; sft < 64; sft <<= 1) nv += __shfl_xor(nv, sft);
    if (half == 0 && (tid & 63) == 0) red[tid >> 6] = nv;
    __syncthreads();
    if (tid == 0) wsn[0] = red[0] + red[1] + b3[0];
  }
}

// ---------------------------------------------------------------------------
// K2: per-batch projections  jp = gather(ops)@W1[:128],  mp = ma@W1[128:]+b1
// one block (256 thr, 4 waves) per batch element; results f16 in ws
// ---------------------------------------------------------------------------
__global__ __launch_bounds__(256) void fjsp_proj(
    const float* __restrict__ ops_emb,
    const float* __restrict__ ma_emb,
    const int*   __restrict__ next_op,
    const float* __restrict__ b1,
    f16* __restrict__ ws)
{
  const int b    = blockIdx.x;
  const int tid  = threadIdx.x;
  const int lane = tid & 63;
  const int wave = tid >> 6;
  const int g    = lane >> 4;
  const int lr   = lane & 15;
  const f16* ws1 = ws + WS1_E;

  // ---- phase J: rows wave*16 + {0..15} (guard < 50) ----
  {
    int jr = wave * 16 + lr; if (jr > NJ_ - 1) jr = NJ_ - 1;
    const int idx = next_op[b * NJ_ + jr];
    const float4* ep = reinterpret_cast<const float4*>(
        ops_emb + ((size_t)b * NOPS_ + idx) * E_);
    f16x8 af[4];
    #pragma unroll
    for (int f = 0; f < 4; ++f) {
      const float4 v0 = ep[8 * f + 2 * g];
      const float4 v1 = ep[8 * f + 2 * g + 1];
      f16x8 a;
      a[0] = (f16)v0.x; a[1] = (f16)v0.y; a[2] = (f16)v0.z; a[3] = (f16)v0.w;
      a[4] = (f16)v1.x; a[5] = (f16)v1.y; a[6] = (f16)v1.z; a[7] = (f16)v1.w;
      af[f] = a;
    }
    f32x4 acc[8];
    #pragma unroll
    for (int c = 0; c < 8; ++c) acc[c] = f32x4{0.f, 0.f, 0.f, 0.f};
    #pragma unroll
    for (int f = 0; f < 4; ++f)
      #pragma unroll
      for (int c = 0; c < 8; ++c) {
        const f16x8 bb = *reinterpret_cast<const f16x8*>(
            ws1 + (size_t)(16 * c + lr) * 256 + 32 * f + 8 * g);
        acc[c] = __builtin_amdgcn_mfma_f32_16x16x32_f16(af[f], bb, acc[c], 0, 0, 0);
      }
    f16* wsJ = ws + WSJ_E + (size_t)b * NJ_ * E_;
    #pragma unroll
    for (int c = 0; c < 8; ++c)
      #pragma unroll
      for (int i = 0; i < 4; ++i) {
        const int row = wave * 16 + 4 * g + i;
        if (row < NJ_) wsJ[row * E_ + 16 * c + lr] = (f16)acc[c][i];
      }
  }

  // ---- phase M: waves 0-2, rows wave*16 + {0..15} (guard < 40), +b1 ----
  if (wave < 3) {
    int mr = wave * 16 + lr; if (mr > NM_ - 1) mr = NM_ - 1;
    const float4* ep = reinterpret_cast<const float4*>(
        ma_emb + ((size_t)b * NM_ + mr) * E_);
    f16x8 af[4];
    #pragma unroll
    for (int f = 0; f < 4; ++f) {
      const float4 v0 = ep[8 * f + 2 * g];
      const float4 v1 = ep[8 * f + 2 * g + 1];
      f16x8 a;
      a[0] = (f16)v0.x; a[1] = (f16)v0.y; a[2] = (f16)v0.z; a[3] = (f16)v0.w;
      a[4] = (f16)v1.x; a[5] = (f16)v1.y; a[6] = (f16)v1.z; a[7] = (f16)v1.w;
      af[f] = a;
    }
    float b1r[8];
    #pragma unroll
    for (int c = 0; c < 8; ++c) b1r[c] = b1[16 * c + lr];
    f32x4 acc[8];
    #pragma unroll
    for (int c = 0; c < 8; ++c)
      acc[c] = f32x4{b1r[c], b1r[c], b1r[c], b1r[c]};
    #pragma unroll
    for (int f = 0; f < 4; ++f)
      #pragma unroll
      for (int c = 0; c < 8; ++c) {
        const f16x8 bb = *reinterpret_cast<const f16x8*>(
            ws1 + (size_t)(16 * c + lr) * 256 + E_ + 32 * f + 8 * g);
        acc[c] = __builtin_amdgcn_mfma_f32_16x16x32_f16(af[f], bb, acc[c], 0, 0, 0);
      }
    f16* wsM = ws + WSM_E + (size_t)b * NM_ * E_;
    #pragma unroll
    for (int c = 0; c < 8; ++c)
      #pragma unroll
      for (int i = 0; i < 4; ++i) {
        const int row = wave * 16 + 4 * g + i;
        if (row < NM_) wsM[row * E_ + 16 * c + lr] = (f16)acc[c][i];
      }
  }
}

// ---------------------------------------------------------------------------
// K3: main pair-logit kernel — 2 blocks (256 thr) per batch element
// ---------------------------------------------------------------------------
__global__ __launch_bounds__(256, 2) void fjsp_main(
    const int*   __restrict__ amask,
    const float* __restrict__ b2,
    const float* __restrict__ W3,
    const float* __restrict__ b3,
    const f16*   __restrict__ ws,
    const float* __restrict__ wsn,
    float* __restrict__ out)
{
  const int bid  = blockIdx.x;
  const int b    = bid >> 1;
  const int sub  = bid & 1;
  const int tid  = threadIdx.x;
  const int lane = tid & 63;
  const int wave = tid >> 6;
  const int g    = lane >> 4;
  const int lr   = lane & 15;

  __shared__ __align__(16) f16 jpL[NJ_][136];
  __shared__ __align__(16) f16 mpL[NM_][136];

  // ---- fill LDS from ws (b128 loads/stores) ----
  {
    const f16x8* srcJ = reinterpret_cast<const f16x8*>(ws + WSJ_E + (size_t)b * NJ_ * E_);
    for (int idx = tid; idx < NJ_ * 16; idx += 256) {
      const int row = idx >> 4, c8 = idx & 15;
      *reinterpret_cast<f16x8*>(&jpL[row][c8 * 8]) = srcJ[idx];
    }
    const f16x8* srcM = reinterpret_cast<const f16x8*>(ws + WSM_E + (size_t)b * NM_ * E_);
    for (int idx = tid; idx < NM_ * 16; idx += 256) {
      const int row = idx >> 4, c8 = idx & 15;
      *reinterpret_cast<f16x8*>(&mpL[row][c8 * 8]) = srcM[idx];
    }
  }

  // ---- W2 fragments (B-operand) + b2/W3 per-column scalars ----
  f16x8 w2f[4][8];
  const f16* ws2 = ws + WS2_E;
  #pragma unroll
  for (int f = 0; f < 4; ++f)
    #pragma unroll
    for (int c = 0; c < 8; ++c)
      w2f[f][c] = *reinterpret_cast<const f16x8*>(
          ws2 + (size_t)(16 * c + lr) * 128 + 32 * f + 8 * g);
  float b2r[8], w3r[8];
  #pragma unroll
  for (int c = 0; c < 8; ++c) { b2r[c] = b2[16 * c + lr]; w3r[c] = W3[16 * c + lr]; }
  const float bias3 = b3[0];

  __syncthreads();

  float* __restrict__ outrow = out + (size_t)b * NCOL_ + 1;
  const int tend = sub ? 125 : 63;

  #pragma unroll 1
  for (int t = sub * 63 + wave; t < tend; t += 4) {
    const int tp0  = t * 16;
    const int rowr = tp0 + lr;
    const int j = rowr / 40;
    const int m = rowr - j * 40;
    f16x8 afr[4];
    #pragma unroll
    for (int f = 0; f < 4; ++f) {
      const f16x8 jv = *reinterpret_cast<const f16x8*>(&jpL[j][32 * f + 8 * g]);
      const f16x8 mv = *reinterpret_cast<const f16x8*>(&mpL[m][32 * f + 8 * g]);
      const f16x8 s  = jv + mv;                       // v_pk_add_f16
      afr[f] = __builtin_elementwise_max(s, (f16x8)(f16)0.0f);  // v_pk_max_f16
    }
    f32x4 acc[8];
    #pragma unroll
    for (int c = 0; c < 8; ++c)
      acc[c] = f32x4{b2r[c], b2r[c], b2r[c], b2r[c]};  // b2 folded into C-init
    #pragma unroll
    for (int f = 0; f < 4; ++f)
      #pragma unroll
      for (int c = 0; c < 8; ++c)
        acc[c] = __builtin_amdgcn_mfma_f32_16x16x32_f16(afr[f], w2f[f][c], acc[c], 0, 0, 0);
    float p0v = 0.f, p1v = 0.f, p2v = 0.f, p3v = 0.f;
    #pragma unroll
    for (int c = 0; c < 8; ++c) {
      p0v = fmaf(fmaxf(acc[c][0], 0.f), w3r[c], p0v);
      p1v = fmaf(fmaxf(acc[c][1], 0.f), w3r[c], p1v);
      p2v = fmaf(fmaxf(acc[c][2], 0.f), w3r[c], p2v);
      p3v = fmaf(fmaxf(acc[c][3], 0.f), w3r[c], p3v);
    }
    #pragma unroll
    for (int s = 1; s < 16; s <<= 1) {
      p0v += __shfl_xor(p0v, s);
      p1v += __shfl_xor(p1v, s);
      p2v += __shfl_xor(p2v, s);
      p3v += __shfl_xor(p3v, s);
    }
    if (lr == 0) {
      const int row = tp0 + 4 * g;
      outrow[row + 0] = p0v + bias3;
      outrow[row + 1] = p1v + bias3;
      outrow[row + 2] = p2v + bias3;
      outrow[row + 3] = p3v + bias3;
    }
  }

  // ---- mask passthrough (int32 bool -> f32), split across the 2 blocks ----
  {
    const int* mrow = amask + (size_t)b * NCOL_;
    float* __restrict__ orow = out + (size_t)BS_ * NCOL_ + (size_t)b * NCOL_;
    const int i0 = sub ? 1001 : 0;
    const int i1 = sub ? NCOL_ : 1001;
    for (int i = i0 + tid; i < i1; i += 256) orow[i] = mrow[i] != 0 ? 1.0f : 0.0f;
  }

  // ---- noop logit ----
  if (sub == 0 && tid == 0) out[(size_t)b * NCOL_] = wsn[0];
}

extern "C" void kernel_launch(void* const* d_in, const int* in_sizes, int n_in,
                              void* d_out, int out_size, void* d_ws, size_t ws_size,
                              hipStream_t stream) {
  (void)in_sizes; (void)n_in; (void)ws_size; (void)out_size;
  f16*   ws  = (f16*)d_ws;
  float* wsn = (float*)((char*)d_ws + WSN_B);

  fjsp_prep<<<dim3(13), dim3(256), 0, stream>>>(
      (const float*)d_in[4],   // dummy
      (const float*)d_in[5],   // W1
      (const float*)d_in[6],   // b1
      (const float*)d_in[7],   // W2
      (const float*)d_in[8],   // b2
      (const float*)d_in[9],   // W3
      (const float*)d_in[10],  // b3
      ws, wsn);

  fjsp_proj<<<dim3(BS_), dim3(256), 0, stream>>>(
      (const float*)d_in[0],   // ops_emb
      (const float*)d_in[1],   // ma_emb
      (const int*)d_in[2],     // next_op
      (const float*)d_in[6],   // b1
      ws);

  fjsp_main<<<dim3(BS_ * 2), dim3(256), 0, stream>>>(
      (const int*)d_in[3],     // action_mask (bool -> int32)
      (const float*)d_in[8],   // b2
      (const float*)d_in[9],   // W3
      (const float*)d_in[10],  // b3
      ws, wsn,
      (float*)d_out);
}

// Round 6
// 38.255 us; speedup vs baseline: 1.4940x; 1.4607x over previous
//
#include <hip/hip_runtime.h>
#include <hip/hip_bf16.h>

#define BS_   256
#define NOPS_ 2000
#define NJ_   50
#define NM_   40
#define E_    128
#define H_    128
#define NCOL_ 2001   // 1 + 50*40

typedef _Float16 f16;
using f16x8 = __attribute__((ext_vector_type(8))) _Float16;
using f32x4 = __attribute__((ext_vector_type(4))) float;

// ---------------------------------------------------------------------------
// Single fused kernel: one block (512 thr, 8 waves) per batch element.
// Phase 1: waves 0-3 jp=gather(ops)@W1[:128] -> LDS f16
//          waves 4-6 mp=ma@W1[128:]+b1      -> LDS f16
//          wave  7   noop MLP (dummy path)   -> LDS scalar
//          all waves: W2 fragments -> regs
// Phase 2: 125 row-tiles of 16 pair-logits, MFMA h1@W2, epilogue dot W3.
// ---------------------------------------------------------------------------
__global__ __launch_bounds__(512, 2) void fjsp_fused(
    const float* __restrict__ ops_emb,
    const float* __restrict__ ma_emb,
    const int*   __restrict__ next_op,
    const int*   __restrict__ amask,
    const float* __restrict__ dummy,
    const float* __restrict__ W1,
    const float* __restrict__ b1,
    const float* __restrict__ W2,
    const float* __restrict__ b2,
    const float* __restrict__ W3,
    const float* __restrict__ b3,
    float* __restrict__ out)
{
  const int b    = blockIdx.x;
  const int tid  = threadIdx.x;
  const int lane = tid & 63;
  const int wave = tid >> 6;
  const int g    = lane >> 4;   // 0..3
  const int lr   = lane & 15;   // 0..15

  __shared__ __align__(16) f16 jpL[NJ_][136];   // 136 f16 = 272B row stride
  __shared__ __align__(16) f16 mpL[NM_][136];
  __shared__ float d1s[128];
  __shared__ float noopL;

  // ---------------- phase 1 ----------------
  if (wave < 7) {
    const int phase = (wave < 4) ? 0 : 1;       // 0: jp rows, 1: mp rows
    const int r0 = (phase ? (wave - 4) : wave) * 16;

    // A fragment: this lane's source row, straight to regs (f32 -> f16)
    f16x8 af[4];
    {
      const float4* ep;
      if (phase == 0) {
        int jr = r0 + lr; if (jr > NJ_ - 1) jr = NJ_ - 1;
        const int idx = next_op[b * NJ_ + jr];
        ep = reinterpret_cast<const float4*>(ops_emb + ((size_t)b * NOPS_ + idx) * E_);
      } else {
        int mr = r0 + lr; if (mr > NM_ - 1) mr = NM_ - 1;
        ep = reinterpret_cast<const float4*>(ma_emb + ((size_t)b * NM_ + mr) * E_);
      }
      #pragma unroll
      for (int f = 0; f < 4; ++f) {
        const float4 v0 = ep[8 * f + 2 * g];
        const float4 v1 = ep[8 * f + 2 * g + 1];
        f16x8 a;
        a[0] = (f16)v0.x; a[1] = (f16)v0.y; a[2] = (f16)v0.z; a[3] = (f16)v0.w;
        a[4] = (f16)v1.x; a[5] = (f16)v1.y; a[6] = (f16)v1.z; a[7] = (f16)v1.w;
        af[f] = a;
      }
    }

    // accumulate (b1 folded into C-init for mp)
    f32x4 acc[8];
    #pragma unroll
    for (int c = 0; c < 8; ++c) {
      const float binit = phase ? b1[16 * c + lr] : 0.f;
      acc[c] = f32x4{binit, binit, binit, binit};
    }
    const int ebase = phase ? E_ : 0;
    #pragma unroll
    for (int f = 0; f < 4; ++f) {
      #pragma unroll
      for (int c = 0; c < 8; ++c) {
        const float* wp = W1 + (size_t)(ebase + 32 * f + 8 * g) * H_ + 16 * c + lr;
        f16x8 bb;
        #pragma unroll
        for (int i = 0; i < 8; ++i) bb[i] = (f16)wp[(size_t)i * H_];
        acc[c] = __builtin_amdgcn_mfma_f32_16x16x32_f16(af[f], bb, acc[c], 0, 0, 0);
      }
    }
    #pragma unroll
    for (int c = 0; c < 8; ++c) {
      const int col = 16 * c + lr;
      #pragma unroll
      for (int i = 0; i < 4; ++i) {
        const int row = r0 + 4 * g + i;
        if (phase == 0) { if (row < NJ_) jpL[row][col] = (f16)acc[c][i]; }
        else            { if (row < NM_) mpL[row][col] = (f16)acc[c][i]; }
      }
    }
  } else {
    // ---- wave 7: noop MLP, 2 hidden units per lane, coalesced L2 loads ----
    float s0 = 0.f, s1 = 0.f;
    #pragma unroll 8
    for (int e = 0; e < 2 * E_; ++e) {
      const float dv = dummy[e];
      s0 = fmaf(dv, W1[(size_t)e * H_ + lane],      s0);
      s1 = fmaf(dv, W1[(size_t)e * H_ + 64 + lane], s1);
    }
    d1s[lane]      = fmaxf(s0 + b1[lane],      0.f);
    d1s[64 + lane] = fmaxf(s1 + b1[64 + lane], 0.f);
    asm volatile("s_waitcnt lgkmcnt(0)" ::: "memory");   // in-wave LDS w->r
    __builtin_amdgcn_wave_barrier();
    float t0 = 0.f, t1 = 0.f;
    #pragma unroll 8
    for (int k = 0; k < H_; ++k) {
      const float dk = d1s[k];                           // broadcast read
      t0 = fmaf(dk, W2[(size_t)k * H_ + lane],      t0);
      t1 = fmaf(dk, W2[(size_t)k * H_ + 64 + lane], t1);
    }
    float nv = fmaxf(t0 + b2[lane],      0.f) * W3[lane]
             + fmaxf(t1 + b2[64 + lane], 0.f) * W3[64 + lane];
    #pragma unroll
    for (int s = 1; s < 64; s <<= 1) nv += __shfl_xor(nv, s);
    if (lane == 0) noopL = nv + b3[0];
  }

  // ---- W2 fragments (every wave; strided L2-hot loads, f32 -> f16) ----
  f16x8 w2f[4][8];
  #pragma unroll
  for (int f = 0; f < 4; ++f) {
    #pragma unroll
    for (int c = 0; c < 8; ++c) {
      const float* wp = W2 + (size_t)(32 * f + 8 * g) * H_ + 16 * c + lr;
      f16x8 bb;
      #pragma unroll
      for (int i = 0; i < 8; ++i) bb[i] = (f16)wp[(size_t)i * H_];
      w2f[f][c] = bb;
    }
  }
  float b2r[8], w3r[8];
  #pragma unroll
  for (int c = 0; c < 8; ++c) { b2r[c] = b2[16 * c + lr]; w3r[c] = W3[16 * c + lr]; }
  const float bias3 = b3[0];

  __syncthreads();

  // ---------------- phase 2: 125 row-tiles across 8 waves ----------------
  float* __restrict__ outrow = out + (size_t)b * NCOL_ + 1;

  #pragma unroll 1
  for (int t = wave; t < 125; t += 8) {
    const int tp0  = t * 16;
    const int rowr = tp0 + lr;
    const int j = rowr / 40;
    const int m = rowr - j * 40;
    f16x8 afr[4];
    #pragma unroll
    for (int f = 0; f < 4; ++f) {
      const f16x8 jv = *reinterpret_cast<const f16x8*>(&jpL[j][32 * f + 8 * g]);
      const f16x8 mv = *reinterpret_cast<const f16x8*>(&mpL[m][32 * f + 8 * g]);
      const f16x8 s  = jv + mv;                                // v_pk_add_f16
      afr[f] = __builtin_elementwise_max(s, (f16x8)(f16)0.0f); // v_pk_max_f16
    }
    f32x4 acc[8];
    #pragma unroll
    for (int c = 0; c < 8; ++c)
      acc[c] = f32x4{b2r[c], b2r[c], b2r[c], b2r[c]};          // b2 in C-init
    #pragma unroll
    for (int f = 0; f < 4; ++f)
      #pragma unroll
      for (int c = 0; c < 8; ++c)
        acc[c] = __builtin_amdgcn_mfma_f32_16x16x32_f16(afr[f], w2f[f][c], acc[c], 0, 0, 0);
    float p0v = 0.f, p1v = 0.f, p2v = 0.f, p3v = 0.f;
    #pragma unroll
    for (int c = 0; c < 8; ++c) {
      p0v = fmaf(fmaxf(acc[c][0], 0.f), w3r[c], p0v);
      p1v = fmaf(fmaxf(acc[c][1], 0.f), w3r[c], p1v);
      p2v = fmaf(fmaxf(acc[c][2], 0.f), w3r[c], p2v);
      p3v = fmaf(fmaxf(acc[c][3], 0.f), w3r[c], p3v);
    }
    #pragma unroll
    for (int s = 1; s < 16; s <<= 1) {
      p0v += __shfl_xor(p0v, s);
      p1v += __shfl_xor(p1v, s);
      p2v += __shfl_xor(p2v, s);
      p3v += __shfl_xor(p3v, s);
    }
    if (lr == 0) {
      const int row = tp0 + 4 * g;
      outrow[row + 0] = p0v + bias3;
      outrow[row + 1] = p1v + bias3;
      outrow[row + 2] = p2v + bias3;
      outrow[row + 3] = p3v + bias3;
    }
  }

  // ---- mask passthrough (int32 bool -> f32), all 512 threads ----
  {
    const int* mrow = amask + (size_t)b * NCOL_;
    float* __restrict__ orow = out + (size_t)BS_ * NCOL_ + (size_t)b * NCOL_;
    for (int i = tid; i < NCOL_; i += 512) orow[i] = mrow[i] != 0 ? 1.0f : 0.0f;
  }

  // ---- noop logit (computed by wave 7 before the barrier) ----
  if (tid == 0) out[(size_t)b * NCOL_] = noopL;
}

extern "C" void kernel_launch(void* const* d_in, const int* in_sizes, int n_in,
                              void* d_out, int out_size, void* d_ws, size_t ws_size,
                              hipStream_t stream) {
  (void)in_sizes; (void)n_in; (void)d_ws; (void)ws_size; (void)out_size;
  fjsp_fused<<<dim3(BS_), dim3(512), 0, stream>>>(
      (const float*)d_in[0],   // ops_emb
      (const float*)d_in[1],   // ma_emb
      (const int*)d_in[2],     // next_op
      (const int*)d_in[3],     // action_mask (bool -> int32)
      (const float*)d_in[4],   // dummy
      (const float*)d_in[5],   // W1
      (const float*)d_in[6],   // b1
      (const float*)d_in[7],   // W2
      (const float*)d_in[8],   // b2
      (const float*)d_in[9],   // W3
      (const float*)d_in[10],  // b3
      (float*)d_out);
}